// Round 2
// baseline (1351.163 us; speedup 1.0000x reference)
//
#include <hip/hip_runtime.h>
#include <hip/hip_bf16.h>

// ---------------------------------------------------------------------------
// HetergatWOConcatFeat — round 2: correctness-first with runtime input-dtype
// detection (bf16 vs f32) and reduced workspace (~66 MB).
// ---------------------------------------------------------------------------

typedef __hip_bfloat16 bf16;

__device__ __forceinline__ float bf2f(bf16 v) { return __bfloat162float(v); }
// Load element i of an INPUT tensor whose dtype is decided by f32 flag.
__device__ __forceinline__ float ldin(const void* p, long i, int f32) {
  return f32 ? ((const float*)p)[i] : bf2f(((const bf16*)p)[i]);
}

// Detect input dtype: read first 2048 elements of hemb0 as bf16. If the data
// is really f32, the mantissa halves decode to huge/NaN values.
__global__ __launch_bounds__(64) void detect_kernel(const void* __restrict__ x,
                                                    int* __restrict__ flag) {
  int tid = threadIdx.x;
  float m = 0.f;
  for (int i = tid; i < 2048; i += 64) {
    float v = fabsf(bf2f(((const bf16*)x)[i]));
    if (!(v <= 1e3f)) v = 1e9f;  // NaN/Inf/big -> force detect
    m = fmaxf(m, v);
  }
#pragma unroll
  for (int off = 32; off; off >>= 1) m = fmaxf(m, __shfl_xor(m, off));
  if (tid == 0) flag[0] = (m > 1e3f) ? 1 : 0;
}

#define BM 64
#define BN 64
#define BKK 16

// C[M,Nc] = A[M,K] @ B[K,Nc], fp32 accumulate.
// amode: 0 = A is ws float, 1 = A is ws bf16, 2 = A is input (flag-dynamic)
// cmode: 0 = C float, 1 = C bf16.  B is always an input tensor (flag-dynamic).
// blockIdx.z batches B/C by strideB/strideC (element strides).
__global__ __launch_bounds__(256) void gemm64(const void* __restrict__ A, int amode,
                                              const void* __restrict__ B,
                                              void* __restrict__ C, int cmode,
                                              int M, int K, int Nc,
                                              long strideB, long strideC,
                                              const int* __restrict__ flag) {
  __shared__ float As[BKK][BM];
  __shared__ float Bs[BKK][BN];
  const int f32 = flag[0];
  const int af32 = (amode == 2) ? f32 : (amode == 0);
  const long zB = (long)blockIdx.z * strideB;
  const long zC = (long)blockIdx.z * strideC;
  const int m0 = blockIdx.x * BM;
  const int n0 = blockIdx.y * BN;
  const int tid = threadIdx.x;
  const int tx = tid & 15, ty = tid >> 4;
  float acc[4][4] = {};
  for (int kt = 0; kt < K; kt += BKK) {
#pragma unroll
    for (int j = 0; j < 4; j++) {
      int i = tid + j * 256;
      int mm = i >> 4;
      int kk = i & 15;
      int gm = m0 + mm;
      float v = 0.f;
      if (gm < M) {
        long idx = (long)gm * K + kt + kk;
        v = af32 ? ((const float*)A)[idx] : bf2f(((const bf16*)A)[idx]);
      }
      As[kk][mm] = v;
    }
#pragma unroll
    for (int j = 0; j < 4; j++) {
      int i = tid + j * 256;
      int kk = i >> 6;
      int nn = i & 63;
      Bs[kk][nn] = ldin(B, zB + (long)(kt + kk) * Nc + n0 + nn, f32);
    }
    __syncthreads();
#pragma unroll
    for (int kk = 0; kk < BKK; kk++) {
      float a[4], b[4];
#pragma unroll
      for (int i = 0; i < 4; i++) {
        a[i] = As[kk][ty * 4 + i];
        b[i] = Bs[kk][tx * 4 + i];
      }
#pragma unroll
      for (int i = 0; i < 4; i++)
#pragma unroll
        for (int j = 0; j < 4; j++) acc[i][j] += a[i] * b[j];
    }
    __syncthreads();
  }
#pragma unroll
  for (int i = 0; i < 4; i++) {
    int gm = m0 + ty * 4 + i;
    if (gm < M) {
#pragma unroll
      for (int j = 0; j < 4; j++) {
        long idx = zC + (long)gm * Nc + n0 + tx * 4 + j;
        if (cmode == 0)
          ((float*)C)[idx] = acc[i][j];
        else
          ((bf16*)C)[idx] = __float2bfloat16(acc[i][j]);
      }
    }
  }
}

// s[n,h] = hp[h,n,:]·asrc[h,:]  ;  t[n,h] = hp[h,n,:]·atrg[h,:]
__global__ __launch_bounds__(256) void st_kernel(const bf16* __restrict__ hp,
                                                 const void* __restrict__ asrc,
                                                 const void* __restrict__ atrg,
                                                 float* __restrict__ sv,
                                                 float* __restrict__ tv, int N,
                                                 const int* __restrict__ flag) {
  const int f32 = flag[0];
  int i = blockIdx.x * 256 + threadIdx.x;
  if (i >= N * 8) return;
  int h = i / N;
  int n = i - h * N;
  const bf16* hpp = hp + ((long)h * N + n) * 64;
  float s = 0.f, t = 0.f;
#pragma unroll
  for (int o = 0; o < 64; o++) {
    float v = bf2f(hpp[o]);
    s += v * ldin(asrc, h * 64 + o, f32);
    t += v * ldin(atrg, h * 64 + o, f32);
  }
  sv[n * 8 + h] = s;
  tv[n * 8 + h] = t;
}

// ---- CSR build ----
__global__ void hist_kernel(const int* __restrict__ trg, int* __restrict__ deg, int E) {
  int e = blockIdx.x * 256 + threadIdx.x;
  if (e < E) atomicAdd(&deg[trg[e]], 1);
}

__global__ __launch_bounds__(1024) void scan_kernel(const int* __restrict__ deg,
                                                    int* __restrict__ row_ptr,
                                                    int* __restrict__ fil, int N) {
  __shared__ int sums[1024];
  int tid = threadIdx.x;
  int chunk = (N + 1023) >> 10;
  int start = tid * chunk;
  int end = start + chunk;
  if (start > N) start = N;
  if (end > N) end = N;
  int s = 0;
  for (int i = start; i < end; i++) s += deg[i];
  sums[tid] = s;
  __syncthreads();
  for (int off = 1; off < 1024; off <<= 1) {
    int add = (tid >= off) ? sums[tid - off] : 0;
    __syncthreads();
    sums[tid] += add;
    __syncthreads();
  }
  int run = (tid > 0) ? sums[tid - 1] : 0;
  for (int i = start; i < end; i++) {
    row_ptr[i] = run;
    fil[i] = run;
    run += deg[i];
  }
  if (tid == 0) row_ptr[N] = sums[1023];
}

__global__ void fill_kernel(const int* __restrict__ src, const int* __restrict__ trg,
                            int* __restrict__ fil, int* __restrict__ col, int E) {
  int e = blockIdx.x * 256 + threadIdx.x;
  if (e >= E) return;
  int t = trg[e];
  int pos = atomicAdd(&fil[t], 1);
  col[pos] = src[e];
}

// GAT aggregation (gather form). One block per target node.
// mode 0: bf16 out[n*512 + h*64 + o] = elu(sum)
// mode 1: float out[n*128 + o] = mean_h(sum)   (caller offsets out by type slot)
#define CAP 128
__global__ __launch_bounds__(256) void aggregate(const bf16* __restrict__ hp,
                                                 const float* __restrict__ sv,
                                                 const float* __restrict__ tv,
                                                 const int* __restrict__ row_ptr,
                                                 const int* __restrict__ col_src,
                                                 void* __restrict__ out, int N, int mode) {
  int n = blockIdx.x;
  int tid = threadIdx.x;
  __shared__ float s_denom[8];
  __shared__ float s_ex[CAP * 8];
  __shared__ int s_src[CAP];
  __shared__ float s_red[512];
  int start = row_ptr[n], end = row_ptr[n + 1];
  int deg = end - start;
  if (tid < 8) s_denom[tid] = 0.f;
  __syncthreads();
  for (int i = tid; i < deg * 8; i += 256) {
    int e = i >> 3, h = i & 7;
    int sidx = col_src[start + e];
    float v = sv[sidx * 8 + h] + tv[n * 8 + h];
    v = v > 0.f ? v : 0.2f * v;
    float ex = __expf(v);
    atomicAdd(&s_denom[h], ex);
    if (e < CAP) {
      s_ex[e * 8 + h] = ex;
      if (h == 0) s_src[e] = sidx;
    }
  }
  __syncthreads();
  int h = tid >> 5, ol = tid & 31;
  float dinv = 1.f / (s_denom[h] + 1e-16f);
  float acc0 = 0.f, acc1 = 0.f;
  for (int e = 0; e < deg; e++) {
    int sidx;
    float ex;
    if (e < CAP) {
      sidx = s_src[e];
      ex = s_ex[e * 8 + h];
    } else {
      sidx = col_src[start + e];
      float v = sv[sidx * 8 + h] + tv[n * 8 + h];
      v = v > 0.f ? v : 0.2f * v;
      ex = __expf(v);
    }
    float a = ex * dinv;
    const bf16* hpp = hp + ((long)h * N + sidx) * 64;
    acc0 += a * bf2f(hpp[ol]);
    acc1 += a * bf2f(hpp[ol + 32]);
  }
  if (mode == 0) {
    float e0 = acc0 > 0.f ? acc0 : expm1f(acc0);
    float e1 = acc1 > 0.f ? acc1 : expm1f(acc1);
    bf16* o16 = (bf16*)out;
    o16[(long)n * 512 + h * 64 + ol] = __float2bfloat16(e0);
    o16[(long)n * 512 + h * 64 + ol + 32] = __float2bfloat16(e1);
  } else {
    s_red[h * 64 + ol] = acc0;
    s_red[h * 64 + ol + 32] = acc1;
    __syncthreads();
    if (tid < 64) {
      float sum = 0.f;
#pragma unroll
      for (int hh = 0; hh < 8; hh++) sum += s_red[hh * 64 + tid];
      ((float*)out)[(long)n * 128 + tid] = sum * 0.125f;
    }
  }
}

// favec[o] = trans1[0,:]·aw1[:,o]
__global__ __launch_bounds__(64) void favec_kernel(const bf16* __restrict__ trans1,
                                                   const void* __restrict__ aw1,
                                                   float* __restrict__ favec,
                                                   const int* __restrict__ flag) {
  const int f32 = flag[0];
  int o = threadIdx.x;
  float acc = 0.f;
  for (int k = 0; k < 256; k++) acc += bf2f(trans1[k]) * ldin(aw1, k * 64 + o, f32);
  favec[o] = acc;
}

// Semantic attention + FC + log_softmax. One wave per node.
__global__ __launch_bounds__(64) void final_kernel(const float* __restrict__ ta,
                                                   const float* __restrict__ favec,
                                                   const void* __restrict__ aw2,
                                                   const void* __restrict__ am,
                                                   const void* __restrict__ fcw,
                                                   const void* __restrict__ fcb,
                                                   void* __restrict__ out, int N,
                                                   const int* __restrict__ flag) {
  const int f32 = flag[0];
  int n = blockIdx.x;
  int o = threadIdx.x;
  __shared__ float s0[64], s1[64];
  float ta0 = ta[(long)n * 128 + o];
  float ta1 = ta[(long)n * 128 + 64 + o];
  s0[o] = ta0;
  s1[o] = ta1;
  __syncthreads();
  float f = favec[o];
  float acc0 = f, acc1 = f;
  for (int k = 0; k < 64; k++) {
    float w = ldin(aw2, k * 64 + o, f32);
    acc0 += s0[k] * w;
    acc1 += s1[k] * w;
  }
  float amv = ldin(am, o, f32);
  float p0 = tanhf(acc0) * amv;
  float p1 = tanhf(acc1) * amv;
#pragma unroll
  for (int off = 32; off > 0; off >>= 1) {
    p0 += __shfl_xor(p0, off);
    p1 += __shfl_xor(p1, off);
  }
  float mx = fmaxf(p0, p1);
  float e0 = __expf(p0 - mx), e1 = __expf(p1 - mx);
  float b0 = e0 / (e0 + e1), b1 = e1 / (e0 + e1);
  float fus = b0 * ta0 + b1 * ta1;
  float l0 = ta0 * ldin(fcw, o * 2 + 0, f32) + ta1 * ldin(fcw, (64 + o) * 2 + 0, f32) +
             fus * ldin(fcw, (128 + o) * 2 + 0, f32);
  float l1 = ta0 * ldin(fcw, o * 2 + 1, f32) + ta1 * ldin(fcw, (64 + o) * 2 + 1, f32) +
             fus * ldin(fcw, (128 + o) * 2 + 1, f32);
#pragma unroll
  for (int off = 32; off > 0; off >>= 1) {
    l0 += __shfl_xor(l0, off);
    l1 += __shfl_xor(l1, off);
  }
  if (o == 0) {
    l0 += ldin(fcb, 0, f32);
    l1 += ldin(fcb, 1, f32);
    float m2 = fmaxf(l0, l1);
    float lse = m2 + logf(__expf(l0 - m2) + __expf(l1 - m2));
    if (f32) {
      ((float*)out)[n * 2 + 0] = l0 - lse;
      ((float*)out)[n * 2 + 1] = l1 - lse;
    } else {
      ((bf16*)out)[n * 2 + 0] = __float2bfloat16(l0 - lse);
      ((bf16*)out)[n * 2 + 1] = __float2bfloat16(l1 - lse);
    }
  }
}

extern "C" void kernel_launch(void* const* d_in, const int* in_sizes, int n_in,
                              void* d_out, int out_size, void* d_ws, size_t ws_size,
                              hipStream_t stream) {
  constexpr int N = 20000, E = 320000, H = 8, F0 = 128, FU = 256, FO = 64;
  const void* hemb[2] = {d_in[0], d_in[1]};
  const void* W[2] = {d_in[2], d_in[3]};
  const void* gw[2][2] = {{d_in[4], d_in[7]}, {d_in[10], d_in[13]}};
  const void* gasrc[2][2] = {{d_in[5], d_in[8]}, {d_in[11], d_in[14]}};
  const void* gatrg[2][2] = {{d_in[6], d_in[9]}, {d_in[12], d_in[15]}};
  const void* aw1 = d_in[16];
  const void* aw2 = d_in[17];
  const void* am = d_in[18];
  const void* fcw = d_in[19];
  const void* fcb = d_in[20];
  const int* edge[2] = {(const int*)d_in[21], (const int*)d_in[22]};

  char* p = (char*)d_ws;
  auto alloc = [&](size_t bytes) -> void* {
    void* r = (void*)p;
    p += (bytes + 255) & ~(size_t)255;
    return r;
  };
  int* flag = (int*)alloc(4);
  bf16* trans = (bf16*)alloc((size_t)N * FU * 2);        // 10.24 MB
  bf16* hp = (bf16*)alloc((size_t)H * N * FO * 2);       // 20.48 MB
  bf16* xbuf = (bf16*)alloc((size_t)N * H * FO * 2);     // 20.48 MB
  float* sv = (float*)alloc((size_t)N * H * 4);          // 0.64 MB
  float* tv = (float*)alloc((size_t)N * H * 4);          // 0.64 MB
  float* ta = (float*)alloc((size_t)N * 2 * FO * 4);     // 10.24 MB
  float* favec = (float*)alloc(FO * 4);
  int* deg[2];
  int* rp[2];
  int* fil[2];
  int* col[2];
  for (int t = 0; t < 2; t++) {
    deg[t] = (int*)alloc((size_t)N * 4);
    rp[t] = (int*)alloc((size_t)(N + 1) * 4);
    fil[t] = (int*)alloc((size_t)N * 4);
    col[t] = (int*)alloc((size_t)E * 4);
  }

  detect_kernel<<<1, 64, 0, stream>>>(hemb[0], flag);

  for (int t = 0; t < 2; t++) {
    hipMemsetAsync(deg[t], 0, (size_t)N * 4, stream);
    hist_kernel<<<(E + 255) / 256, 256, 0, stream>>>(edge[t] + E, deg[t], E);
    scan_kernel<<<1, 1024, 0, stream>>>(deg[t], rp[t], fil[t], N);
    fill_kernel<<<(E + 255) / 256, 256, 0, stream>>>(edge[t], edge[t] + E, fil[t], col[t], E);
  }

  const int gmx = (N + BM - 1) / BM;  // 313

  for (int t = 0; t < 2; t++) {
    // trans = hemb @ W  [N, FU] (bf16 ws)
    gemm64<<<dim3(gmx, FU / BN, 1), 256, 0, stream>>>(hemb[t], 2, W[t], trans, 1,
                                                      N, F0, FU, 0, 0, flag);
    // hp[h,n,o] layer 0
    gemm64<<<dim3(gmx, 1, H), 256, 0, stream>>>(trans, 1, gw[t][0], hp, 1,
                                                N, FU, FO, (long)FU * FO, (long)N * FO, flag);
    st_kernel<<<(N * H + 255) / 256, 256, 0, stream>>>(hp, gasrc[t][0], gatrg[t][0], sv, tv, N, flag);
    aggregate<<<N, 256, 0, stream>>>(hp, sv, tv, rp[t], col[t], xbuf, N, 0);
    // hp layer 1 (input xbuf [N, 512])
    gemm64<<<dim3(gmx, 1, H), 256, 0, stream>>>(xbuf, 1, gw[t][1], hp, 1,
                                                N, H * FO, FO, (long)(H * FO) * FO, (long)N * FO, flag);
    st_kernel<<<(N * H + 255) / 256, 256, 0, stream>>>(hp, gasrc[t][1], gatrg[t][1], sv, tv, N, flag);
    aggregate<<<N, 256, 0, stream>>>(hp, sv, tv, rp[t], col[t], ta + t * FO, N, 1);
  }

  favec_kernel<<<1, 64, 0, stream>>>(trans, aw1, favec, flag);
  final_kernel<<<N, 64, 0, stream>>>(ta, favec, aw2, am, fcw, fcb, d_out, N, flag);
}